// Round 6
// baseline (187.274 us; speedup 1.0000x reference)
//
#include <hip/hip_runtime.h>

// DiagLRConv via bf16 MFMA: out[n,o,h,w] = sum_{k,i} fw[o,i,k] * x[n,i,h+k-2,w+k-2]
// x: (16,16,512,512) fp32, fw: (16,16,5) fp32, out fp32.
// GEMM view per 16x16 tile: D(px,o) = sum_K X'(px,K) W'(o,K), K=(tap,i) 80->96 pad,
// 3x mfma_f32_16x16x32_bf16, fp32 accumulate. A=X' (m=px), B=W' (n=o) so each
// lane's f32x4 acc holds 4 consecutive px -> dwordx4 stores.

#define HH    512
#define WW    512
#define CH    16
#define KK    5
#define IMG   (HH * WW)
#define CHIMG (CH * IMG)

#define HT  8            // output rows per block
#define WT  64           // output px per block
#define RI  12           // staged input rows (HT + 4 halo)
#define WI  68           // staged input px   (WT + 4 halo)
#define WIP 69           // padded row stride in 16B units (bank-derotate quarters)
#define NCHUNK (RI * 2)  // (row, channel-half) chunks

typedef __attribute__((ext_vector_type(8))) short bf16x8;
typedef __attribute__((ext_vector_type(4))) float f32x4;
typedef __attribute__((ext_vector_type(4))) int   i32x4;

union I4S8 { i32x4 i; bf16x8 s; };

__device__ __forceinline__ unsigned cvt_pk_bf16(float lo, float hi) {
    unsigned r;
    asm("v_cvt_pk_bf16_f32 %0, %1, %2" : "=v"(r) : "v"(lo), "v"(hi));
    return r;
}

// NOTE (R2): never cap VGPRs with __launch_bounds__ minwaves — acc spilled.
__global__ __launch_bounds__(256)
void diag_conv_mfma(const float* __restrict__ x,
                    const float* __restrict__ fw,
                    float* __restrict__ out)
{
    // LDS: [chunk = ri*2 + ch_half][wi] -> 16B = 8 bf16 (channels half*8..+7).
    // Row stride WIP=69 units: quarter bank rotations {0,20,8,28} (conflict fix).
    __shared__ i32x4 xl[NCHUNK * WIP];   // 24*69*16B = 25.9 KB -> 6 blocks/CU LDS-wise

    const int tid = threadIdx.x;

    // Bijective XCD swizzle: 8192 blocks = 8 XCDs x 1024 contiguous (2 images each).
    const int bid = blockIdx.x;
    const int swz = ((bid & 7) << 10) | (bid >> 3);
    const int n  = swz >> 9;          // 0..15
    const int ht = (swz >> 3) & 63;   // 0..63
    const int wt = swz & 7;           // 0..7
    const int h0 = ht * HT;
    const int w0 = wt * WT;

    const int wv   = tid >> 6;
    const int lane = tid & 63;

    const float* __restrict__ xn = x + (size_t)n * CHIMG;

    // ---------------- stage: load-all -> cvt-all -> write-all ---------------
    // 24 (ri,ih) units round-robin over 4 waves; lane = px 0..63. All 48 global
    // loads issued before any use -> one latency exposure, max MLP.
    const float* pu[6];
    bool oku[6];
#pragma unroll
    for (int u = 0; u < 6; ++u) {
        const int unit = u * 4 + wv;
        const int ri = unit >> 1;
        const int ih = unit & 1;
        const int r  = h0 - 2 + ri;
        const int w  = w0 - 2 + lane;
        oku[u] = ((unsigned)r < (unsigned)HH) & ((unsigned)w < (unsigned)WW);
        const int rc = r < 0 ? 0 : (r > HH - 1 ? HH - 1 : r);
        const int wc = w < 0 ? 0 : (w > WW - 1 ? WW - 1 : w);
        pu[u] = xn + (size_t)(ih * 8) * IMG + (size_t)rc * WW + wc;
    }
    float rv[6][8];
#pragma unroll
    for (int u = 0; u < 6; ++u)
#pragma unroll
        for (int j = 0; j < 8; ++j)
            rv[u][j] = pu[u][(size_t)j * IMG];
#pragma unroll
    for (int u = 0; u < 6; ++u) {
        const int unit = u * 4 + wv;
        i32x4 pk;
        if (!oku[u]) {
#pragma unroll
            for (int j = 0; j < 8; ++j) rv[u][j] = 0.f;
        }
        pk.x = (int)cvt_pk_bf16(rv[u][0], rv[u][1]);
        pk.y = (int)cvt_pk_bf16(rv[u][2], rv[u][3]);
        pk.z = (int)cvt_pk_bf16(rv[u][4], rv[u][5]);
        pk.w = (int)cvt_pk_bf16(rv[u][6], rv[u][7]);
        xl[unit * WIP + lane] = pk;
    }
    // tail px 64..67: 96 threads, one (unit, px) each
    if (tid < 96) {
        const int unit = tid >> 2;          // 0..23
        const int wi   = 64 + (tid & 3);
        const int ri = unit >> 1;
        const int ih = unit & 1;
        const int r  = h0 - 2 + ri;
        const int w  = w0 - 2 + wi;
        const bool ok = ((unsigned)r < (unsigned)HH) & ((unsigned)w < (unsigned)WW);
        const int rc = r < 0 ? 0 : (r > HH - 1 ? HH - 1 : r);
        const int wc = w < 0 ? 0 : (w > WW - 1 ? WW - 1 : w);
        const float* __restrict__ p8 = xn + (size_t)(ih * 8) * IMG + (size_t)rc * WW + wc;
        float v[8];
#pragma unroll
        for (int j = 0; j < 8; ++j) v[j] = p8[(size_t)j * IMG];
        if (!ok) {
#pragma unroll
            for (int j = 0; j < 8; ++j) v[j] = 0.f;
        }
        i32x4 pk;
        pk.x = (int)cvt_pk_bf16(v[0], v[1]);
        pk.y = (int)cvt_pk_bf16(v[2], v[3]);
        pk.z = (int)cvt_pk_bf16(v[4], v[5]);
        pk.w = (int)cvt_pk_bf16(v[6], v[7]);
        xl[unit * WIP + wi] = pk;
    }

    // ---------------- B fragments (weights) ---------------------------------
    // lane: n = o = l&15 ; K-slot = (l>>4)*8+j -> tap = 2s + (l>>5),
    // i = ((l>>4)&1)*8 + j. s=2 upper half pairs tap 5 (pad) -> zero.
    const int px  = lane & 15;           // also o for the B build
    const int ihl = (lane >> 4) & 1;
    const int tb  = lane >> 5;

    bf16x8 wfrag[3];
#pragma unroll
    for (int s = 0; s < 3; ++s) {
        const int tap = 2 * s + tb;
        I4S8 a;
        a.i = (i32x4){0, 0, 0, 0};
        if (tap < KK) {
            const float* __restrict__ wp = fw + ((size_t)px * CH + ihl * 8) * KK + tap;
            a.i.x = (int)cvt_pk_bf16(wp[0 * KK], wp[1 * KK]);
            a.i.y = (int)cvt_pk_bf16(wp[2 * KK], wp[3 * KK]);
            a.i.z = (int)cvt_pk_bf16(wp[4 * KK], wp[5 * KK]);
            a.i.w = (int)cvt_pk_bf16(wp[6 * KK], wp[7 * KK]);
        }
        wfrag[s] = a.s;
    }

    __syncthreads();

    // ---------------- MFMA: 2 rows x 4 px-groups x 3 K-slices ---------------
    f32x4 acc[2][4];
#pragma unroll
    for (int yy = 0; yy < 2; ++yy)
#pragma unroll
        for (int g = 0; g < 4; ++g) acc[yy][g] = (f32x4){0.f, 0.f, 0.f, 0.f};

    const int ybase = wv * 2;
#pragma unroll
    for (int yy = 0; yy < 2; ++yy) {
#pragma unroll
        for (int s = 0; s < 3; ++s) {
            const int tap = 2 * s + tb;               // per-lane
            int ri = ybase + yy + tap;
            ri = ri > RI - 1 ? RI - 1 : ri;           // pad-tap lanes only (W=0)
            const int c = ri * 2 + ihl;
#pragma unroll
            for (int g = 0; g < 4; ++g) {
                int wi = g * 16 + px + tap;
                wi = wi > WI - 1 ? WI - 1 : wi;       // pad-tap lanes only (W=0)
                I4S8 b;
                b.i = xl[c * WIP + wi];               // ds_read_b128
                acc[yy][g] = __builtin_amdgcn_mfma_f32_16x16x32_bf16(
                    b.s, wfrag[s], acc[yy][g], 0, 0, 0);   // A=X', B=W'
            }
        }
    }

    // ---------------- store: D row = px = (l>>4)*4+reg, col = o = l&15 ------
    // Each lane: 4 consecutive px for one o -> dwordx4.
    float* __restrict__ on = out + (size_t)n * CHIMG;
    const int o   = lane & 15;
    const int pq  = (lane >> 4) << 2;    // px offset within group
#pragma unroll
    for (int yy = 0; yy < 2; ++yy) {
        const int h = h0 + ybase + yy;
#pragma unroll
        for (int g = 0; g < 4; ++g) {
            float* __restrict__ dst =
                on + (size_t)o * IMG + (size_t)h * WW + (w0 + g * 16 + pq);
            *(f32x4*)dst = acc[yy][g];   // 16B aligned
        }
    }
}

extern "C" void kernel_launch(void* const* d_in, const int* in_sizes, int n_in,
                              void* d_out, int out_size, void* d_ws, size_t ws_size,
                              hipStream_t stream)
{
    const float* x  = (const float*)d_in[0];
    const float* fw = (const float*)d_in[1];
    float* out      = (float*)d_out;

    // 8192 blocks = 16 n x 64 ht x 8 wt
    diag_conv_mfma<<<dim3(8192), dim3(256), 0, stream>>>(x, fw, out);
}